// Round 3
// baseline (259.819 us; speedup 1.0000x reference)
//
#include <hip/hip_runtime.h>

// SSIM, fused: reflect-pad(1) + five 3x3 box filters + elementwise formula.
// NCHW 32x3x384x640 fp32.
//
// R3: latency-optimized. One thread = one output float4 (4 pixels of one row).
// All 18 global loads (3 rows x {float4 + 2 halo scalars} x 2 tensors) are
// independent and issued before any use -> ~150B MLP per thread, 92k waves.
// Vertical reuse is served by L1/L2 (rows hit 3x) instead of registers.
// XCD swizzle: contiguous 1/8 of the image per XCD for L2 row locality.

constexpr int HH = 384;
constexpr int WW = 640;
constexpr int GPR = WW / 4;        // 160 float4-groups per row
constexpr int BLK = 256;
constexpr float C1 = 0.01f * 0.01f;
constexpr float C2 = 0.03f * 0.03f;

__global__ __launch_bounds__(BLK) void ssim_kernel(
    const float* __restrict__ x,
    const float* __restrict__ y,
    float* __restrict__ out,
    int blocks_per_xcd, int total_threads)
{
    // XCD swizzle: hw assigns block b to XCD b%8; give each XCD a contiguous
    // chunk of the image so row-overlap reuse stays within one L2.
    const int b   = blockIdx.x;
    const int vb  = (b & 7) * blocks_per_xcd + (b >> 3);
    const int t   = vb * BLK + threadIdx.x;
    if (t >= total_threads) return;

    const int g     = t % GPR;          // float4-group within row
    const int rowg  = t / GPR;          // global row across planes
    const int h     = rowg % HH;
    const int plane = rowg / HH;

    const int w4 = g * 4;
    const size_t pbase = (size_t)plane * (size_t)(HH * WW);
    const float* __restrict__ xp = x + pbase;
    const float* __restrict__ yp = y + pbase;

    // reflect (jnp 'reflect': edge NOT repeated): -1 -> 1, N -> N-2
    const int hm = (h == 0)      ? 1      : (h - 1);
    const int hq = (h == HH - 1) ? HH - 2 : (h + 1);
    const int wm = (w4 == 0)       ? 1      : (w4 - 1);
    const int wq = (w4 + 4 == WW)  ? WW - 2 : (w4 + 4);

    const float* __restrict__ xr0 = xp + (size_t)hm * WW;
    const float* __restrict__ xr1 = xp + (size_t)h  * WW;
    const float* __restrict__ xr2 = xp + (size_t)hq * WW;
    const float* __restrict__ yr0 = yp + (size_t)hm * WW;
    const float* __restrict__ yr1 = yp + (size_t)h  * WW;
    const float* __restrict__ yr2 = yp + (size_t)hq * WW;

    // ---- issue all 18 loads, fully independent ----
    const float4 xv0 = *(const float4*)(xr0 + w4);
    const float4 xv1 = *(const float4*)(xr1 + w4);
    const float4 xv2 = *(const float4*)(xr2 + w4);
    const float4 yv0 = *(const float4*)(yr0 + w4);
    const float4 yv1 = *(const float4*)(yr1 + w4);
    const float4 yv2 = *(const float4*)(yr2 + w4);
    const float xl0 = xr0[wm], xh0 = xr0[wq];
    const float xl1 = xr1[wm], xh1 = xr1[wq];
    const float xl2 = xr2[wm], xh2 = xr2[wq];
    const float yl0 = yr0[wm], yh0 = yr0[wq];
    const float yl1 = yr1[wm], yh1 = yr1[wq];
    const float yl2 = yr2[wm], yh2 = yr2[wq];

    const float ax0[6] = {xl0, xv0.x, xv0.y, xv0.z, xv0.w, xh0};
    const float ax1[6] = {xl1, xv1.x, xv1.y, xv1.z, xv1.w, xh1};
    const float ax2[6] = {xl2, xv2.x, xv2.y, xv2.z, xv2.w, xh2};
    const float ay0[6] = {yl0, yv0.x, yv0.y, yv0.z, yv0.w, yh0};
    const float ay1[6] = {yl1, yv1.x, yv1.y, yv1.z, yv1.w, yh1};
    const float ay2[6] = {yl2, yv2.x, yv2.y, yv2.z, yv2.w, yh2};

    // vertical sums per column (separable), then horizontal 3-tap
    float vx[6], vy[6], vxx[6], vyy[6], vxy[6];
#pragma unroll
    for (int c = 0; c < 6; ++c) {
        vx[c]  = ax0[c] + ax1[c] + ax2[c];
        vy[c]  = ay0[c] + ay1[c] + ay2[c];
        vxx[c] = fmaf(ax2[c], ax2[c], fmaf(ax1[c], ax1[c], ax0[c] * ax0[c]));
        vyy[c] = fmaf(ay2[c], ay2[c], fmaf(ay1[c], ay1[c], ay0[c] * ay0[c]));
        vxy[c] = fmaf(ax2[c], ay2[c], fmaf(ax1[c], ay1[c], ax0[c] * ay0[c]));
    }

    const float inv9 = 1.0f / 9.0f;
    float4 o;
    float* ov = &o.x;
#pragma unroll
    for (int c = 0; c < 4; ++c) {
        const float sx  = vx[c]  + vx[c+1]  + vx[c+2];
        const float sy  = vy[c]  + vy[c+1]  + vy[c+2];
        const float sxx = vxx[c] + vxx[c+1] + vxx[c+2];
        const float syy = vyy[c] + vyy[c+1] + vyy[c+2];
        const float sxy = vxy[c] + vxy[c+1] + vxy[c+2];

        const float mux  = sx * inv9;
        const float muy  = sy * inv9;
        const float varx = fmaf(-mux, mux, sxx * inv9);
        const float vary = fmaf(-muy, muy, syy * inv9);
        const float cov  = fmaf(-mux, muy, sxy * inv9);

        const float num = fmaf(2.0f * mux, muy, C1) * fmaf(2.0f, cov, C2);
        const float den = (fmaf(mux, mux, muy * muy) + C1) * (varx + vary + C2);
#if __has_builtin(__builtin_amdgcn_rcpf)
        float s = num * __builtin_amdgcn_rcpf(den);
#else
        float s = num / den;
#endif
        s = fminf(fmaxf(s, 0.0f), 1.0f);
        ov[c] = s;
    }
    *(float4*)(out + pbase + (size_t)h * WW + w4) = o;
}

extern "C" void kernel_launch(void* const* d_in, const int* in_sizes, int n_in,
                              void* d_out, int out_size, void* d_ws, size_t ws_size,
                              hipStream_t stream) {
    const float* x = (const float*)d_in[0];
    const float* y = (const float*)d_in[1];
    float* out = (float*)d_out;

    const int planes = in_sizes[0] / (HH * WW);            // 96
    const int total_threads = planes * HH * GPR;           // 5,898,240
    const int nblocks = (total_threads + BLK - 1) / BLK;   // 23040
    const int blocks_per_xcd = (nblocks + 7) / 8;          // 2880

    ssim_kernel<<<nblocks, BLK, 0, stream>>>(x, y, out, blocks_per_xcd,
                                             total_threads);
}

// Round 5
// 242.795 us; speedup vs baseline: 1.0701x; 1.0701x over previous
//
#include <hip/hip_runtime.h>

// SSIM, fused: reflect-pad(1) + five 3x3 box filters + elementwise formula.
// NCHW 32x3x384x640 fp32.
//
// R4b: rolling-window (1.17x read amplification, no LDS) + explicit software
// pipeline (prefetch distance 1, 3 rows in flight at start) + halo via
// __shfl of the neighboring lane's float4 (exec-masked scalar fallback only
// at wave/row edges). Nontemporal stores (via native ext_vector type) keep
// inputs L3-resident.

constexpr int HH = 384;
constexpr int WW = 640;
constexpr int KROWS = 12;          // output rows per thread (loads 14 rows)
constexpr int TX = 160;            // float4-columns per row
constexpr int TY = 2;              // row strips per block -> 320 thr = 5 waves
constexpr float C1 = 0.01f * 0.01f;
constexpr float C2 = 0.03f * 0.03f;

typedef float nfloat4 __attribute__((ext_vector_type(4)));  // native vec for builtins

struct Row { float4 xv, yv; float xl, xh, yl, yh; };
struct HS  { float hx[4], hy[4], hxx[4], hyy[4], hxy[4]; };

__global__ __launch_bounds__(TX * TY, 4) void ssim_kernel(
    const float* __restrict__ x,
    const float* __restrict__ y,
    float* __restrict__ out)
{
    const int tx   = threadIdx.x;
    const int lane = (threadIdx.y * TX + tx) & 63;
    const int w4   = tx * 4;
    const int h0   = (blockIdx.y * TY + threadIdx.y) * KROWS;
    const size_t pbase = (size_t)blockIdx.z * (size_t)(HH * WW);
    const float* __restrict__ xp = x + pbase;
    const float* __restrict__ yp = y + pbase;

    // lanes that cannot get their halo from a wave neighbor
    const bool nl = (tx == 0)      || (lane == 0);
    const bool nr = (tx == TX - 1) || (lane == 63);
    // reflect (jnp 'reflect': edge NOT repeated)
    const int wm = (w4 == 0)       ? 1      : (w4 - 1);
    const int wq = (w4 + 4 == WW)  ? WW - 2 : (w4 + 4);

    auto loadrow = [&](int r) -> Row {
        r = (r < 0) ? 1 : ((r >= HH) ? (HH - 2) : r);
        const float* __restrict__ xr = xp + (size_t)r * WW;
        const float* __restrict__ yr = yp + (size_t)r * WW;
        Row o;
        o.xv = *(const float4*)(xr + w4);
        o.yv = *(const float4*)(yr + w4);
        o.xl = nl ? xr[wm] : 0.0f;     // exec-masked edge loads
        o.xh = nr ? xr[wq] : 0.0f;
        o.yl = nl ? yr[wm] : 0.0f;
        o.yh = nr ? yr[wq] : 0.0f;
        return o;
    };

    auto hsum = [&](const Row& r) -> HS {
        // neighbor halo via shfl (all lanes provide), fallback at edges
        const float sxl = __shfl_up(r.xv.w, 1);
        const float sxh = __shfl_down(r.xv.x, 1);
        const float syl = __shfl_up(r.yv.w, 1);
        const float syh = __shfl_down(r.yv.x, 1);
        const float ax[6] = { nl ? r.xl : sxl, r.xv.x, r.xv.y, r.xv.z, r.xv.w,
                              nr ? r.xh : sxh };
        const float ay[6] = { nl ? r.yl : syl, r.yv.x, r.yv.y, r.yv.z, r.yv.w,
                              nr ? r.yh : syh };
        HS o;
#pragma unroll
        for (int c = 0; c < 4; ++c) {
            o.hx[c]  = ax[c] + ax[c+1] + ax[c+2];
            o.hy[c]  = ay[c] + ay[c+1] + ay[c+2];
            o.hxx[c] = fmaf(ax[c+2], ax[c+2], fmaf(ax[c+1], ax[c+1], ax[c]*ax[c]));
            o.hyy[c] = fmaf(ay[c+2], ay[c+2], fmaf(ay[c+1], ay[c+1], ay[c]*ay[c]));
            o.hxy[c] = fmaf(ax[c+2], ay[c+2], fmaf(ax[c+1], ay[c+1], ax[c]*ay[c]));
        }
        return o;
    };

    // ---- pipeline startup: 3 rows in flight ----
    Row a = loadrow(h0 - 1);
    Row b = loadrow(h0);
    Row cur = loadrow(h0 + 1);

    HS win[3];
    win[0] = hsum(a);
    win[1] = hsum(b);

    const float inv9 = 1.0f / 9.0f;

#pragma unroll
    for (int i = 0; i < KROWS; ++i) {
        // prefetch row h0+i+2 while we consume row h0+i+1
        Row nxt = cur;
        if (i < KROWS - 1) nxt = loadrow(h0 + i + 2);

        win[(i + 2) % 3] = hsum(cur);

        const HS& w0 = win[0];
        const HS& w1 = win[1];
        const HS& w2 = win[2];
        nfloat4 o;
#pragma unroll
        for (int c = 0; c < 4; ++c) {
            const float sx  = w0.hx[c]  + w1.hx[c]  + w2.hx[c];
            const float sy  = w0.hy[c]  + w1.hy[c]  + w2.hy[c];
            const float sxx = w0.hxx[c] + w1.hxx[c] + w2.hxx[c];
            const float syy = w0.hyy[c] + w1.hyy[c] + w2.hyy[c];
            const float sxy = w0.hxy[c] + w1.hxy[c] + w2.hxy[c];

            const float mux  = sx * inv9;
            const float muy  = sy * inv9;
            const float varx = fmaf(-mux, mux, sxx * inv9);
            const float vary = fmaf(-muy, muy, syy * inv9);
            const float cov  = fmaf(-mux, muy, sxy * inv9);

            const float num = fmaf(2.0f * mux, muy, C1) * fmaf(2.0f, cov, C2);
            const float den = (fmaf(mux, mux, muy * muy) + C1) * (varx + vary + C2);
#if __has_builtin(__builtin_amdgcn_rcpf)
            float s = num * __builtin_amdgcn_rcpf(den);
#else
            float s = num / den;
#endif
            s = fminf(fmaxf(s, 0.0f), 1.0f);
            o[c] = s;
        }
        __builtin_nontemporal_store(
            o, (nfloat4*)(out + pbase + (size_t)(h0 + i) * WW + w4));

        cur = nxt;
    }
}

extern "C" void kernel_launch(void* const* d_in, const int* in_sizes, int n_in,
                              void* d_out, int out_size, void* d_ws, size_t ws_size,
                              hipStream_t stream) {
    const float* x = (const float*)d_in[0];
    const float* y = (const float*)d_in[1];
    float* out = (float*)d_out;

    const int planes = in_sizes[0] / (HH * WW);        // 96
    dim3 grid(1, HH / (TY * KROWS), planes);           // (1, 16, 96) = 1536 blocks
    dim3 block(TX, TY);                                // 320 threads = 5 waves
    ssim_kernel<<<grid, block, 0, stream>>>(x, y, out);
}